// Round 14
// baseline (219.433 us; speedup 1.0000x reference)
//
#include <hip/hip_runtime.h>
#include <stdint.h>
#include <stddef.h>

// Problem geometry
#define BROWS  16384
#define SROWS  8192
#define FDIM   512
#define NCHUNK 8
#define SCHUNK (SROWS / NCHUNK)     // 1024
#define BM     256                  // X rows per block
#define BN     256                  // S cols per S-tile
#define BK     32                   // K per staged chunk (3-buffer pipeline)
#define NSTILE (SCHUNK / BN)        // 4
#define NKC    (FDIM / BK)          // 16
#define NC     (NSTILE * NKC)       // 64 chunks per block

#define LOG2E 1.44269504088896340736f

typedef __bf16 bf16x8 __attribute__((ext_vector_type(8)));
typedef float  f32x4  __attribute__((ext_vector_type(4)));

__device__ inline void gload16(const void* g, void* l) {
  __builtin_amdgcn_global_load_lds(
      (const __attribute__((address_space(1))) void*)g,
      (__attribute__((address_space(3))) void*)l, 16, 0, 0);
}

// ---------------------------------------------------------------------------
// Prep S: f32 -> bf16, lc2[s] = log2(coeff[s]) - g*log2e*||s||^2  (validated)
// ---------------------------------------------------------------------------
__global__ __launch_bounds__(256) void prep_s_kernel(
    const float* __restrict__ S, const float* __restrict__ coeff,
    const float* __restrict__ gamma, __bf16* __restrict__ Sb,
    float* __restrict__ lc2)
{
  const int lane = threadIdx.x & 63;
  const int wid  = threadIdx.x >> 6;
  const int row  = (blockIdx.x << 2) + wid;
  const float* src = S + ((size_t)row << 9) + (lane << 3);
  float4 a = ((const float4*)src)[0];
  float4 b = ((const float4*)src)[1];
  float sq = a.x*a.x + a.y*a.y + a.z*a.z + a.w*a.w +
             b.x*b.x + b.y*b.y + b.z*b.z + b.w*b.w;
  bf16x8 v;
  v[0]=(__bf16)a.x; v[1]=(__bf16)a.y; v[2]=(__bf16)a.z; v[3]=(__bf16)a.w;
  v[4]=(__bf16)b.x; v[5]=(__bf16)b.y; v[6]=(__bf16)b.z; v[7]=(__bf16)b.w;
  *(bf16x8*)(Sb + ((size_t)row << 9) + (lane << 3)) = v;
  #pragma unroll
  for (int m = 1; m < 64; m <<= 1) sq += __shfl_xor(sq, m, 64);
  if (lane == 0) lc2[row] = log2f(coeff[row]) - gamma[0] * LOG2E * sq;
}

// ---------------------------------------------------------------------------
// Prep X: f32 -> bf16, ex[row] = exp2(-g*log2e*||x||^2)
// ---------------------------------------------------------------------------
__global__ __launch_bounds__(256) void prep_x_kernel(
    const float* __restrict__ X, const float* __restrict__ gamma,
    __bf16* __restrict__ Xb, float* __restrict__ ex)
{
  const int lane = threadIdx.x & 63;
  const int wid  = threadIdx.x >> 6;
  const int row  = (blockIdx.x << 2) + wid;
  const float* src = X + ((size_t)row << 9) + (lane << 3);
  float4 a = ((const float4*)src)[0];
  float4 b = ((const float4*)src)[1];
  float sq = a.x*a.x + a.y*a.y + a.z*a.z + a.w*a.w +
             b.x*b.x + b.y*b.y + b.z*b.z + b.w*b.w;
  bf16x8 v;
  v[0]=(__bf16)a.x; v[1]=(__bf16)a.y; v[2]=(__bf16)a.z; v[3]=(__bf16)a.w;
  v[4]=(__bf16)b.x; v[5]=(__bf16)b.y; v[6]=(__bf16)b.z; v[7]=(__bf16)b.w;
  *(bf16x8*)(Xb + ((size_t)row << 9) + (lane << 3)) = v;
  #pragma unroll
  for (int m = 1; m < 64; m <<= 1) sq += __shfl_xor(sq, m, 64);
  if (lane == 0) ex[row] = exp2f(-gamma[0] * LOG2E * sq);
}

// ---------------------------------------------------------------------------
// Main: 2D register-blocked fused RBF-GEMM — T4 counted-vmcnt pipeline.
// 8 waves (2M x 4N), wave = 128x64 (acc 128 AGPR), 16x16x32 MFMA.
// BK=32 chunks TRIPLE-buffered (3 x 32 KB = A16K+B16K each): stage chunk
// c+2 during chunk c; at chunk top s_waitcnt vmcnt(4) — own chunk's loads
// done, next chunk's 4 stay IN FLIGHT across the barrier (never drain to 0
// except the last chunk). One barrier per chunk. Race-free: buf (c+2)%3
// was last read at chunk c-1; two barriers separate that from the write.
// Swizzle: rows are 64 B; byte ^= ((row&3)<<4) via pre-swizzled global src
// (linear gload_lds dst) + same XOR on ds_read addr -> beat-balanced b128.
// A-affine XCD map (mtile = bx&63) keeps the A-tile in one XCD's L2 (R13:
// halved FETCH). Score accumulated in LDS (R12). setprio around MFMA (T5).
// ---------------------------------------------------------------------------
__global__ __launch_bounds__(512, 2) void ocsvm_main_kernel(
    const __bf16* __restrict__ Xb, const __bf16* __restrict__ Sb,
    const float* __restrict__ lc2, const float* __restrict__ ex,
    const float* __restrict__ gamma, float* __restrict__ partials)
{
  __shared__ char lds[98304];         // 3 x (A 16 KB + B 16 KB)
  __shared__ float score_lds[BM];     // per-row score accumulator
  const int tid  = threadIdx.x;
  const int lane = tid & 63;
  const int wid  = tid >> 6;
  const int wm   = wid >> 2;        // 0..1  (M group: 128 rows)
  const int wn   = wid & 3;         // 0..3  (N group: 64 cols)
  const int lr   = lane & 15;
  const int hi   = lane >> 4;       // 0..3 (k-quarter)

  const int bx      = blockIdx.x;
  const int mtile   = bx & 63;        // XCD = bx%8 = mtile%8 -> A-affine
  const int chunkid = bx >> 6;
  const int m0      = mtile * BM;
  const int chunk0  = chunkid * SCHUNK;

  const float K2 = 2.0f * gamma[0] * LOG2E;

  const char* xb = (const char*)Xb;
  const char* sb = (const char*)Sb;

  // staging: 2 rounds x 1024 segs; t -> row r = t>>2, 16B-seg t&3,
  // source byte pre-swizzled so linear LDS == swizzled layout (rule #21)
#define STAGE(bufsel, c)                                                      \
  { const int st_ = (c) >> 4, kc_ = (c) & 15;                                 \
    _Pragma("unroll")                                                         \
    for (int j = 0; j < 2; ++j) {                                             \
      const int t = (j << 9) + tid;                                           \
      const int r = t >> 2;                                                   \
      const int so = ((t & 3) << 4) ^ ((r & 3) << 4);                         \
      gload16(xb + (((size_t)(m0 + r)) << 10) + (kc_ << 6) + so,              \
              &lds[(bufsel) * 32768 + (t << 4)]);                             \
      gload16(sb + (((size_t)(chunk0 + (st_ << 8) + r)) << 10) + (kc_ << 6) + so, \
              &lds[(bufsel) * 32768 + 16384 + (t << 4)]);                     \
    } }

  // frag-read offsets (row stride 64 B, XOR swizzle on k-byte)
  const int kswz  = (hi << 4) ^ ((lr & 3) << 4);
  const int aoff0 = (wm << 13) + (lr << 6) + kswz;            // + mi*1024
  const int boff0 = 16384 + (wn << 12) + (lr << 6) + kswz;    // + ni*1024

  STAGE(0, 0);
  STAGE(1, 1);
  if (tid < BM) score_lds[tid] = 0.0f;   // init before first barrier

  f32x4 acc[8][4];
  #pragma unroll
  for (int mi = 0; mi < 8; ++mi)
    #pragma unroll
    for (int ni = 0; ni < 4; ++ni) acc[mi][ni] = (f32x4){0.f, 0.f, 0.f, 0.f};

  int rb = 0;                      // read-buffer index (c % 3)
  for (int c = 0; c < NC; ++c) {
    if (c + 1 < NC) {
      asm volatile("s_waitcnt vmcnt(4)" ::: "memory");  // own loads done; next 4 in flight
    } else {
      asm volatile("s_waitcnt vmcnt(0)" ::: "memory");  // final chunk: drain
    }
    __builtin_amdgcn_s_barrier();
    asm volatile("" ::: "memory");

    int tb = rb + 2; if (tb >= 3) tb -= 3;
    if (c + 2 < NC) STAGE(tb, c + 2);    // post-barrier: 3-buffer race-free

    const char* base = &lds[rb * 32768];
    __builtin_amdgcn_s_setprio(1);
    bf16x8 b0 = *(const bf16x8*)(base + boff0);
    bf16x8 b1 = *(const bf16x8*)(base + boff0 + 1024);
    bf16x8 b2 = *(const bf16x8*)(base + boff0 + 2048);
    bf16x8 b3 = *(const bf16x8*)(base + boff0 + 3072);
    #pragma unroll
    for (int mh = 0; mh < 2; ++mh) {
      const char* pa = base + aoff0 + mh * 4096;
      bf16x8 a0 = *(const bf16x8*)(pa);
      bf16x8 a1 = *(const bf16x8*)(pa + 1024);
      bf16x8 a2 = *(const bf16x8*)(pa + 2048);
      bf16x8 a3 = *(const bf16x8*)(pa + 3072);
      const int mb = mh << 2;
      acc[mb+0][0] = __builtin_amdgcn_mfma_f32_16x16x32_bf16(a0, b0, acc[mb+0][0], 0, 0, 0);
      acc[mb+0][1] = __builtin_amdgcn_mfma_f32_16x16x32_bf16(a0, b1, acc[mb+0][1], 0, 0, 0);
      acc[mb+0][2] = __builtin_amdgcn_mfma_f32_16x16x32_bf16(a0, b2, acc[mb+0][2], 0, 0, 0);
      acc[mb+0][3] = __builtin_amdgcn_mfma_f32_16x16x32_bf16(a0, b3, acc[mb+0][3], 0, 0, 0);
      acc[mb+1][0] = __builtin_amdgcn_mfma_f32_16x16x32_bf16(a1, b0, acc[mb+1][0], 0, 0, 0);
      acc[mb+1][1] = __builtin_amdgcn_mfma_f32_16x16x32_bf16(a1, b1, acc[mb+1][1], 0, 0, 0);
      acc[mb+1][2] = __builtin_amdgcn_mfma_f32_16x16x32_bf16(a1, b2, acc[mb+1][2], 0, 0, 0);
      acc[mb+1][3] = __builtin_amdgcn_mfma_f32_16x16x32_bf16(a1, b3, acc[mb+1][3], 0, 0, 0);
      acc[mb+2][0] = __builtin_amdgcn_mfma_f32_16x16x32_bf16(a2, b0, acc[mb+2][0], 0, 0, 0);
      acc[mb+2][1] = __builtin_amdgcn_mfma_f32_16x16x32_bf16(a2, b1, acc[mb+2][1], 0, 0, 0);
      acc[mb+2][2] = __builtin_amdgcn_mfma_f32_16x16x32_bf16(a2, b2, acc[mb+2][2], 0, 0, 0);
      acc[mb+2][3] = __builtin_amdgcn_mfma_f32_16x16x32_bf16(a2, b3, acc[mb+2][3], 0, 0, 0);
      acc[mb+3][0] = __builtin_amdgcn_mfma_f32_16x16x32_bf16(a3, b0, acc[mb+3][0], 0, 0, 0);
      acc[mb+3][1] = __builtin_amdgcn_mfma_f32_16x16x32_bf16(a3, b1, acc[mb+3][1], 0, 0, 0);
      acc[mb+3][2] = __builtin_amdgcn_mfma_f32_16x16x32_bf16(a3, b2, acc[mb+3][2], 0, 0, 0);
      acc[mb+3][3] = __builtin_amdgcn_mfma_f32_16x16x32_bf16(a3, b3, acc[mb+3][3], 0, 0, 0);
    }
    __builtin_amdgcn_s_setprio(0);

    // S-tile boundary: fold exp into LDS score, reset acc
    if ((c & 15) == 15) {
      const int st = c >> 4;
      const float* lc = lc2 + chunk0 + (st << 8) + (wn << 6) + lr;
      const float l0 = lc[0], l1 = lc[16], l2 = lc[32], l3 = lc[48];
      #pragma unroll
      for (int mi = 0; mi < 8; ++mi)
        #pragma unroll
        for (int j = 0; j < 4; ++j) {
          float v = __builtin_amdgcn_exp2f(__builtin_fmaf(K2, acc[mi][0][j], l0))
                  + __builtin_amdgcn_exp2f(__builtin_fmaf(K2, acc[mi][1][j], l1))
                  + __builtin_amdgcn_exp2f(__builtin_fmaf(K2, acc[mi][2][j], l2))
                  + __builtin_amdgcn_exp2f(__builtin_fmaf(K2, acc[mi][3][j], l3));
          v += __shfl_xor(v, 1, 64);
          v += __shfl_xor(v, 2, 64);
          v += __shfl_xor(v, 4, 64);
          v += __shfl_xor(v, 8, 64);
          if (lr == 0)   // C layout (m89): row = (lane>>4)*4 + reg
            atomicAdd(&score_lds[(wm << 7) + (mi << 4) + (hi << 2) + j], v);
          acc[mi][j < 1 ? 0 : j] = acc[mi][j];  // no-op to keep structure simple
        }
      #pragma unroll
      for (int mi = 0; mi < 8; ++mi)
        #pragma unroll
        for (int ni = 0; ni < 4; ++ni) acc[mi][ni] = (f32x4){0.f, 0.f, 0.f, 0.f};
    }

    ++rb; if (rb >= 3) rb = 0;
  }

  __syncthreads();   // all ds_add_f32 retired
  if (tid < BM) {
    const int row = m0 + tid;
    partials[(size_t)chunkid * BROWS + row] = score_lds[tid] * ex[row];
  }
#undef STAGE
}

// ---------------------------------------------------------------------------
// Final: sum 8 chunk partials, subtract rho.
// ---------------------------------------------------------------------------
__global__ __launch_bounds__(256) void reduce_kernel(
    const float* __restrict__ partials, const float* __restrict__ rho,
    float* __restrict__ out)
{
  const int i = blockIdx.x * 256 + threadIdx.x;
  float s = 0.0f;
  #pragma unroll
  for (int k = 0; k < NCHUNK; ++k) s += partials[(size_t)k * BROWS + i];
  out[i] = s - rho[0];
}

extern "C" void kernel_launch(void* const* d_in, const int* in_sizes, int n_in,
                              void* d_out, int out_size, void* d_ws, size_t ws_size,
                              hipStream_t stream) {
  const float* X     = (const float*)d_in[0];   // [16384,512] f32
  const float* S     = (const float*)d_in[1];   // [8192,512]  f32
  const float* coeff = (const float*)d_in[2];   // [1,8192]    f32
  const float* rho   = (const float*)d_in[3];   // [1]         f32
  const float* gamma = (const float*)d_in[4];   // scalar      f32
  float* out = (float*)d_out;

  // ws: Sb 8MB | Xb 16MB | lc2 32KB | ex 64KB | partials 512KB  (~24.6 MB)
  char* ws = (char*)d_ws;
  __bf16* Sb    = (__bf16*)ws;
  __bf16* Xbuf  = (__bf16*)(ws + ((size_t)SROWS * FDIM * 2));
  float*  lc2   = (float*)(ws + ((size_t)SROWS * FDIM * 2) + ((size_t)BROWS * FDIM * 2));
  float*  ex    = lc2 + SROWS;
  float*  parts = ex + BROWS;

  prep_s_kernel<<<SROWS / 4, 256, 0, stream>>>(S, coeff, gamma, Sb, lc2);
  prep_x_kernel<<<BROWS / 4, 256, 0, stream>>>(X, gamma, Xbuf, ex);
  ocsvm_main_kernel<<<NCHUNK * (BROWS / BM), 512, 0, stream>>>(Xbuf, Sb, lc2, ex, gamma, parts);
  reduce_kernel<<<BROWS / 256, 256, 0, stream>>>(parts, rho, out);
}

// Round 16
// 194.097 us; speedup vs baseline: 1.1305x; 1.1305x over previous
//
#include <hip/hip_runtime.h>
#include <stdint.h>
#include <stddef.h>

// Problem geometry
#define BROWS  16384
#define SROWS  8192
#define FDIM   512
#define NCHUNK 8
#define SCHUNK (SROWS / NCHUNK)     // 1024
#define BM     256                  // X rows per block
#define BN     128                  // S cols per S-tile
#define BK     32                   // K per staged chunk
#define NSTILE (SCHUNK / BN)        // 8
#define NKC    (FDIM / BK)          // 16
#define NC     (NSTILE * NKC)       // 128 chunks per block

#define LOG2E 1.44269504088896340736f

typedef __bf16 bf16x8 __attribute__((ext_vector_type(8)));
typedef float  f32x4  __attribute__((ext_vector_type(4)));

__device__ inline void gload16(const void* g, void* l) {
  __builtin_amdgcn_global_load_lds(
      (const __attribute__((address_space(1))) void*)g,
      (__attribute__((address_space(3))) void*)l, 16, 0, 0);
}

// ---------------------------------------------------------------------------
// Prep S: f32 -> bf16, lc2[s] = log2(coeff[s]) - g*log2e*||s||^2  (validated)
// ---------------------------------------------------------------------------
__global__ __launch_bounds__(256) void prep_s_kernel(
    const float* __restrict__ S, const float* __restrict__ coeff,
    const float* __restrict__ gamma, __bf16* __restrict__ Sb,
    float* __restrict__ lc2)
{
  const int lane = threadIdx.x & 63;
  const int wid  = threadIdx.x >> 6;
  const int row  = (blockIdx.x << 2) + wid;
  const float* src = S + ((size_t)row << 9) + (lane << 3);
  float4 a = ((const float4*)src)[0];
  float4 b = ((const float4*)src)[1];
  float sq = a.x*a.x + a.y*a.y + a.z*a.z + a.w*a.w +
             b.x*b.x + b.y*b.y + b.z*b.z + b.w*b.w;
  bf16x8 v;
  v[0]=(__bf16)a.x; v[1]=(__bf16)a.y; v[2]=(__bf16)a.z; v[3]=(__bf16)a.w;
  v[4]=(__bf16)b.x; v[5]=(__bf16)b.y; v[6]=(__bf16)b.z; v[7]=(__bf16)b.w;
  *(bf16x8*)(Sb + ((size_t)row << 9) + (lane << 3)) = v;
  #pragma unroll
  for (int m = 1; m < 64; m <<= 1) sq += __shfl_xor(sq, m, 64);
  if (lane == 0) lc2[row] = log2f(coeff[row]) - gamma[0] * LOG2E * sq;
}

// ---------------------------------------------------------------------------
// Prep X: f32 -> bf16, ex[row] = exp2(-g*log2e*||x||^2)
// ---------------------------------------------------------------------------
__global__ __launch_bounds__(256) void prep_x_kernel(
    const float* __restrict__ X, const float* __restrict__ gamma,
    __bf16* __restrict__ Xb, float* __restrict__ ex)
{
  const int lane = threadIdx.x & 63;
  const int wid  = threadIdx.x >> 6;
  const int row  = (blockIdx.x << 2) + wid;
  const float* src = X + ((size_t)row << 9) + (lane << 3);
  float4 a = ((const float4*)src)[0];
  float4 b = ((const float4*)src)[1];
  float sq = a.x*a.x + a.y*a.y + a.z*a.z + a.w*a.w +
             b.x*b.x + b.y*b.y + b.z*b.z + b.w*b.w;
  bf16x8 v;
  v[0]=(__bf16)a.x; v[1]=(__bf16)a.y; v[2]=(__bf16)a.z; v[3]=(__bf16)a.w;
  v[4]=(__bf16)b.x; v[5]=(__bf16)b.y; v[6]=(__bf16)b.z; v[7]=(__bf16)b.w;
  *(bf16x8*)(Xb + ((size_t)row << 9) + (lane << 3)) = v;
  #pragma unroll
  for (int m = 1; m < 64; m <<= 1) sq += __shfl_xor(sq, m, 64);
  if (lane == 0) ex[row] = exp2f(-gamma[0] * LOG2E * sq);
}

// ---------------------------------------------------------------------------
// Main: 2D register-blocked fused RBF-GEMM — conflict-free swizzle +
// 2 blocks/CU (two independent barrier domains overlap each other's stalls).
// Block = 256 thr = 4 waves (2M x 2N); wave = 128x64 (M_rep=8, N_rep=4,
// acc 128 AGPR) -> same 384 B/MFMA LDS ratio as R14, half the LDS/block
// (A 16 KB + B 8 KB per BK=32 chunk, triple-buffered = 72 KB) -> 2 blocks/CU.
// Swizzle (64-B rows): stored seg p = s ^ ((row>>1)&3) via pre-swizzled
// global source (linear gload_lds dst, rule #21); read kswz =
// (hi ^ ((lr>>1)&3))<<4. Every 8-lane beat hits all 8 bank-groups once.
// Pipeline: T4 counted vmcnt — stage chunk c+2 post-barrier, vmcnt(6) at
// chunk top (own 6 loads done, next 6 in flight across the barrier; drain
// only on the last chunk). One barrier per chunk; 3-buffer race-free.
// lc2 preloaded to LDS so epilogue reads are lgkm-side (no vmcnt drain).
// A-affine XCD map (mtile = bx&63). Score in LDS (ds_add). setprio (T5).
// ---------------------------------------------------------------------------
__global__ __launch_bounds__(256, 2) void ocsvm_main_kernel(
    const __bf16* __restrict__ Xb, const __bf16* __restrict__ Sb,
    const float* __restrict__ lc2, const float* __restrict__ ex,
    const float* __restrict__ gamma, float* __restrict__ partials)
{
  __shared__ char lds[73728];         // 3 x (A 16 KB + B 8 KB)
  __shared__ float lcl[SCHUNK];       // this chunk's lc2 (4 KB)
  __shared__ float score_lds[BM];     // per-row score accumulator
  const int tid  = threadIdx.x;
  const int lane = tid & 63;
  const int wid  = tid >> 6;
  const int wm   = wid >> 1;        // 0..1  (M group: 128 rows)
  const int wn   = wid & 1;         // 0..1  (N group: 64 cols)
  const int lr   = lane & 15;
  const int hi   = lane >> 4;       // 0..3 (k-quarter)

  const int bx      = blockIdx.x;
  const int mtile   = bx & 63;        // XCD = bx%8 = mtile%8 -> A-affine
  const int chunkid = bx >> 6;
  const int m0      = mtile * BM;
  const int chunk0  = chunkid * SCHUNK;

  const float K2 = 2.0f * gamma[0] * LOG2E;

  const char* xb = (const char*)Xb;
  const char* sb = (const char*)Sb;

  // stage one BK=32 chunk: A 16 KB (4 rounds) + B 8 KB (2 rounds),
  // linear LDS dst, source seg pre-swizzled: s = (pos&3) ^ ((row>>1)&3)
#define STAGE(bufsel, c)                                                      \
  { const int st_ = (c) >> 4, kc_ = (c) & 15;                                 \
    _Pragma("unroll")                                                         \
    for (int r_ = 0; r_ < 4; ++r_) {                                          \
      const int g = (r_ << 8) + tid;                                          \
      const int rw = g >> 2;                                                  \
      const int s_ = (g & 3) ^ ((rw >> 1) & 3);                               \
      gload16(xb + (((size_t)(m0 + rw)) << 10) + (kc_ << 6) + (s_ << 4),      \
              &lds[(bufsel) * 24576 + (g << 4)]);                             \
    }                                                                         \
    _Pragma("unroll")                                                         \
    for (int r_ = 0; r_ < 2; ++r_) {                                          \
      const int g = (r_ << 8) + tid;                                          \
      const int rw = g >> 2;                                                  \
      const int s_ = (g & 3) ^ ((rw >> 1) & 3);                               \
      gload16(sb + (((size_t)(chunk0 + (st_ << 7) + rw)) << 10) + (kc_ << 6)  \
                 + (s_ << 4),                                                 \
              &lds[(bufsel) * 24576 + 16384 + (g << 4)]);                     \
    } }

  // frag-read offsets: row*64 + (hi ^ ((lr>>1)&3))*16 — beat-conflict-free
  const int kswz  = (hi ^ ((lr >> 1) & 3)) << 4;
  const int aoff0 = (wm << 13) + (lr << 6) + kswz;            // + mi*1024
  const int boff0 = 16384 + (wn << 12) + (lr << 6) + kswz;    // + ni*1024

  // lc2 chunk -> LDS (1 load/thread), then the two prologue chunks
  gload16((const char*)(lc2 + chunk0) + (tid << 4), ((char*)lcl) + (tid << 4));
  STAGE(0, 0);
  STAGE(1, 1);
  score_lds[tid] = 0.0f;   // 256 threads cover BM

  f32x4 acc[8][4];
  #pragma unroll
  for (int mi = 0; mi < 8; ++mi)
    #pragma unroll
    for (int ni = 0; ni < 4; ++ni) acc[mi][ni] = (f32x4){0.f, 0.f, 0.f, 0.f};

  int rb = 0;                      // read-buffer index (c % 3)
  for (int c = 0; c < NC; ++c) {
    if (c + 1 < NC) {
      asm volatile("s_waitcnt vmcnt(6)" ::: "memory");  // own chunk done; next 6 in flight
    } else {
      asm volatile("s_waitcnt vmcnt(0)" ::: "memory");  // final chunk: drain
    }
    __builtin_amdgcn_s_barrier();
    asm volatile("" ::: "memory");

    int tb = rb + 2; if (tb >= 3) tb -= 3;
    if (c + 2 < NC) STAGE(tb, c + 2);    // post-barrier: 3-buffer race-free

    const char* base = &lds[rb * 24576];
    __builtin_amdgcn_s_setprio(1);
    bf16x8 b0 = *(const bf16x8*)(base + boff0);
    bf16x8 b1 = *(const bf16x8*)(base + boff0 + 1024);
    bf16x8 b2 = *(const bf16x8*)(base + boff0 + 2048);
    bf16x8 b3 = *(const bf16x8*)(base + boff0 + 3072);
    #pragma unroll
    for (int mh = 0; mh < 2; ++mh) {
      const char* pa = base + aoff0 + mh * 4096;
      bf16x8 a0 = *(const bf16x8*)(pa);
      bf16x8 a1 = *(const bf16x8*)(pa + 1024);
      bf16x8 a2 = *(const bf16x8*)(pa + 2048);
      bf16x8 a3 = *(const bf16x8*)(pa + 3072);
      const int mb = mh << 2;
      acc[mb+0][0] = __builtin_amdgcn_mfma_f32_16x16x32_bf16(a0, b0, acc[mb+0][0], 0, 0, 0);
      acc[mb+0][1] = __builtin_amdgcn_mfma_f32_16x16x32_bf16(a0, b1, acc[mb+0][1], 0, 0, 0);
      acc[mb+0][2] = __builtin_amdgcn_mfma_f32_16x16x32_bf16(a0, b2, acc[mb+0][2], 0, 0, 0);
      acc[mb+0][3] = __builtin_amdgcn_mfma_f32_16x16x32_bf16(a0, b3, acc[mb+0][3], 0, 0, 0);
      acc[mb+1][0] = __builtin_amdgcn_mfma_f32_16x16x32_bf16(a1, b0, acc[mb+1][0], 0, 0, 0);
      acc[mb+1][1] = __builtin_amdgcn_mfma_f32_16x16x32_bf16(a1, b1, acc[mb+1][1], 0, 0, 0);
      acc[mb+1][2] = __builtin_amdgcn_mfma_f32_16x16x32_bf16(a1, b2, acc[mb+1][2], 0, 0, 0);
      acc[mb+1][3] = __builtin_amdgcn_mfma_f32_16x16x32_bf16(a1, b3, acc[mb+1][3], 0, 0, 0);
      acc[mb+2][0] = __builtin_amdgcn_mfma_f32_16x16x32_bf16(a2, b0, acc[mb+2][0], 0, 0, 0);
      acc[mb+2][1] = __builtin_amdgcn_mfma_f32_16x16x32_bf16(a2, b1, acc[mb+2][1], 0, 0, 0);
      acc[mb+2][2] = __builtin_amdgcn_mfma_f32_16x16x32_bf16(a2, b2, acc[mb+2][2], 0, 0, 0);
      acc[mb+2][3] = __builtin_amdgcn_mfma_f32_16x16x32_bf16(a2, b3, acc[mb+2][3], 0, 0, 0);
      acc[mb+3][0] = __builtin_amdgcn_mfma_f32_16x16x32_bf16(a3, b0, acc[mb+3][0], 0, 0, 0);
      acc[mb+3][1] = __builtin_amdgcn_mfma_f32_16x16x32_bf16(a3, b1, acc[mb+3][1], 0, 0, 0);
      acc[mb+3][2] = __builtin_amdgcn_mfma_f32_16x16x32_bf16(a3, b2, acc[mb+3][2], 0, 0, 0);
      acc[mb+3][3] = __builtin_amdgcn_mfma_f32_16x16x32_bf16(a3, b3, acc[mb+3][3], 0, 0, 0);
    }
    __builtin_amdgcn_s_setprio(0);

    // S-tile boundary: fold exp into LDS score, reset acc.
    // lc values come from LDS (lgkm) -> no vmcnt pollution of the pipeline.
    if ((c & 15) == 15) {
      const int st = c >> 4;
      const int lbase = (st << 7) + (wn << 6) + lr;
      const float l0 = lcl[lbase];
      const float l1 = lcl[lbase + 16];
      const float l2 = lcl[lbase + 32];
      const float l3 = lcl[lbase + 48];
      #pragma unroll
      for (int mi = 0; mi < 8; ++mi)
        #pragma unroll
        for (int j = 0; j < 4; ++j) {
          float v = __builtin_amdgcn_exp2f(__builtin_fmaf(K2, acc[mi][0][j], l0))
                  + __builtin_amdgcn_exp2f(__builtin_fmaf(K2, acc[mi][1][j], l1))
                  + __builtin_amdgcn_exp2f(__builtin_fmaf(K2, acc[mi][2][j], l2))
                  + __builtin_amdgcn_exp2f(__builtin_fmaf(K2, acc[mi][3][j], l3));
          v += __shfl_xor(v, 1, 64);
          v += __shfl_xor(v, 2, 64);
          v += __shfl_xor(v, 4, 64);
          v += __shfl_xor(v, 8, 64);
          if (lr == 0)   // C layout (m89): row = (lane>>4)*4 + reg
            atomicAdd(&score_lds[(wm << 7) + (mi << 4) + (hi << 2) + j], v);
        }
      #pragma unroll
      for (int mi = 0; mi < 8; ++mi)
        #pragma unroll
        for (int ni = 0; ni < 4; ++ni) acc[mi][ni] = (f32x4){0.f, 0.f, 0.f, 0.f};
    }

    ++rb; if (rb >= 3) rb = 0;
  }

  __syncthreads();   // all ds_add retired
  {
    const int row = m0 + tid;
    partials[(size_t)chunkid * BROWS + row] = score_lds[tid] * ex[row];
  }
#undef STAGE
}

// ---------------------------------------------------------------------------
// Final: sum 8 chunk partials, subtract rho.
// ---------------------------------------------------------------------------
__global__ __launch_bounds__(256) void reduce_kernel(
    const float* __restrict__ partials, const float* __restrict__ rho,
    float* __restrict__ out)
{
  const int i = blockIdx.x * 256 + threadIdx.x;
  float s = 0.0f;
  #pragma unroll
  for (int k = 0; k < NCHUNK; ++k) s += partials[(size_t)k * BROWS + i];
  out[i] = s - rho[0];
}

extern "C" void kernel_launch(void* const* d_in, const int* in_sizes, int n_in,
                              void* d_out, int out_size, void* d_ws, size_t ws_size,
                              hipStream_t stream) {
  const float* X     = (const float*)d_in[0];   // [16384,512] f32
  const float* S     = (const float*)d_in[1];   // [8192,512]  f32
  const float* coeff = (const float*)d_in[2];   // [1,8192]    f32
  const float* rho   = (const float*)d_in[3];   // [1]         f32
  const float* gamma = (const float*)d_in[4];   // scalar      f32
  float* out = (float*)d_out;

  // ws: Sb 8MB | Xb 16MB | lc2 32KB | ex 64KB | partials 512KB  (~24.6 MB)
  char* ws = (char*)d_ws;
  __bf16* Sb    = (__bf16*)ws;
  __bf16* Xbuf  = (__bf16*)(ws + ((size_t)SROWS * FDIM * 2));
  float*  lc2   = (float*)(ws + ((size_t)SROWS * FDIM * 2) + ((size_t)BROWS * FDIM * 2));
  float*  ex    = lc2 + SROWS;
  float*  parts = ex + BROWS;

  prep_s_kernel<<<SROWS / 4, 256, 0, stream>>>(S, coeff, gamma, Sb, lc2);
  prep_x_kernel<<<BROWS / 4, 256, 0, stream>>>(X, gamma, Xbuf, ex);
  ocsvm_main_kernel<<<NCHUNK * (BROWS / BM), 256, 0, stream>>>(Xbuf, Sb, lc2, ex, gamma, parts);
  reduce_kernel<<<BROWS / 256, 256, 0, stream>>>(parts, rho, out);
}